// Round 2
// baseline (63.471 us; speedup 1.0000x reference)
//
#include <hip/hip_runtime.h>
#include <cstddef>

// c = 1 - 0.9^10 : closed form of 10 steps of h <- h - 0.1*(h - W_x) from h0=0
#define FREE_C 0.6513215599f

// coef(p,j) = C[p,j,p^j] * sgn(p^j), where
//   C-sign: parity of swap count = p1&j0 ^ p2&j1 ^ p2&j0 (Cl(3,0), all metric +1)
//   sgn(k) = (-1)^{r(r-1)/2}, r=popcount(k): + for grades 0,1; - for grades 2,3
__device__ __forceinline__ float coef_pj(int p, int j) {
    int s1 = (((p >> 1) & j) ^ ((p >> 2) & (j >> 1)) ^ ((p >> 2) & j)) & 1;
    int k = p ^ j;
    int r = (k & 1) + ((k >> 1) & 1) + ((k >> 2) & 1);
    int s2 = (r >= 2) ? 1 : 0;
    return ((s1 ^ s2) & 1) ? -1.0f : 1.0f;
}

// T[o][p] = c * sum_{h,j} W_in[h][j] * coef(p,j) * W_out[o][h][p^j]
// one block per o; 256 threads stride over h; shuffle+LDS reduction
__global__ __launch_bounds__(256) void build_T_kernel(
    const float* __restrict__ W_in,   // [H][8]
    const float* __restrict__ W_out,  // [O][H][8]
    float* __restrict__ T,            // [O][8]
    int H)
{
    const int o = blockIdx.x;
    const int t = threadIdx.x;

    float acc[8];
#pragma unroll
    for (int p = 0; p < 8; ++p) acc[p] = 0.0f;

    for (int h = t; h < H; h += 256) {
        const float4* wi = reinterpret_cast<const float4*>(W_in + (size_t)h * 8);
        float4 a0 = wi[0], a1 = wi[1];
        const float4* wo = reinterpret_cast<const float4*>(W_out + ((size_t)o * H + h) * 8);
        float4 b0 = wo[0], b1 = wo[1];

        float win[8]  = {a0.x, a0.y, a0.z, a0.w, a1.x, a1.y, a1.z, a1.w};
        float wout[8] = {b0.x, b0.y, b0.z, b0.w, b1.x, b1.y, b1.z, b1.w};

#pragma unroll
        for (int p = 0; p < 8; ++p) {
            float s = 0.0f;
#pragma unroll
            for (int j = 0; j < 8; ++j) {
                // coef_pj folds to a compile-time +-1 under full unroll
                s += coef_pj(p, j) * win[j] * wout[p ^ j];
            }
            acc[p] += s;
        }
    }

    // intra-wave (64-lane) butterfly reduce for each of the 8 accumulators
#pragma unroll
    for (int p = 0; p < 8; ++p) {
#pragma unroll
        for (int off = 32; off > 0; off >>= 1)
            acc[p] += __shfl_down(acc[p], off, 64);
    }

    __shared__ float lds[4][8];
    const int wave = t >> 6;
    const int lane = t & 63;
    if (lane == 0) {
#pragma unroll
        for (int p = 0; p < 8; ++p) lds[wave][p] = acc[p];
    }
    __syncthreads();
    if (t < 8) {
        float s = lds[0][t] + lds[1][t] + lds[2][t] + lds[3][t];
        T[o * 8 + t] = FREE_C * s;
    }
}

// out[b][o] = sum_p x[b][p] * T[o][p]
// T staged in LDS with stride 9 (pad) -> max 2-way bank aliasing (free on wave64)
__global__ __launch_bounds__(256) void apply_T_kernel(
    const float* __restrict__ x,   // [B][8]
    const float* __restrict__ T,   // [O][8]
    float* __restrict__ out,       // [B][O]
    int B, int O)
{
    extern __shared__ float Ts[];  // [O][9]
    const int tid = threadIdx.x;
    for (int idx = tid; idx < O * 8; idx += 256) {
        int oo = idx >> 3;
        int pp = idx & 7;
        Ts[oo * 9 + pp] = T[idx];
    }
    __syncthreads();

    const int total = B * O;
    const int stride = gridDim.x * 256;
    for (int i = blockIdx.x * 256 + tid; i < total; i += stride) {
        const int b = i / O;
        const int o = i - b * O;
        const float4* xp = reinterpret_cast<const float4*>(x + (size_t)b * 8);
        float4 x0 = xp[0], x1 = xp[1];  // broadcast across the 128 threads sharing b (L1 hit)
        const float* t = Ts + o * 9;
        float s = x0.x * t[0] + x0.y * t[1] + x0.z * t[2] + x0.w * t[3]
                + x1.x * t[4] + x1.y * t[5] + x1.z * t[6] + x1.w * t[7];
        out[i] = s;
    }
}

extern "C" void kernel_launch(void* const* d_in, const int* in_sizes, int n_in,
                              void* d_out, int out_size, void* d_ws, size_t ws_size,
                              hipStream_t stream) {
    const float* x_mv  = (const float*)d_in[0];  // [B,8]     f32
    const float* W_in  = (const float*)d_in[1];  // [H,1,8]   f32
    const float* W_out = (const float*)d_in[2];  // [O,H,8]   f32
    float* out = (float*)d_out;                  // [B,O]     f32

    const int B = in_sizes[0] / 8;
    const int H = in_sizes[1] / 8;
    const int O = in_sizes[2] / (8 * H);

    float* T = (float*)d_ws;  // O*8 floats (4 KB)

    build_T_kernel<<<O, 256, 0, stream>>>(W_in, W_out, T, H);

    const int total = B * O;
    int grid = (total + 255) / 256;
    if (grid > 2048) grid = 2048;
    const size_t lds_bytes = (size_t)O * 9 * sizeof(float);
    apply_T_kernel<<<grid, 256, lds_bytes, stream>>>(x_mv, T, out, B, O);
}

// Round 3
// 62.510 us; speedup vs baseline: 1.0154x; 1.0154x over previous
//
#include <hip/hip_runtime.h>
#include <cstddef>

// c = 1 - 0.9^10 : closed form of 10 steps of h <- h - 0.1*(h - W_x) from h0=0
#define FREE_C 0.6513215599f

// coef(p,j) = C[p,j,p^j] * sgn(p^j)  (Cl(3,0): all metric +1)
//   C-sign: swap parity = p1&j0 ^ p2&j1 ^ p2&j0
//   sgn(k) = (-1)^{r(r-1)/2}, r=popcount(k): + for grades 0,1; - for grades 2,3
__device__ __forceinline__ float coef_pj(int p, int j) {
    int s1 = (((p >> 1) & j) ^ ((p >> 2) & (j >> 1)) ^ ((p >> 2) & j)) & 1;
    int k = p ^ j;
    int r = (k & 1) + ((k >> 1) & 1) + ((k >> 2) & 1);
    int s2 = (r >= 2) ? 1 : 0;
    return ((s1 ^ s2) & 1) ? -1.0f : 1.0f;
}

// T[o][p] = c * sum_{h,j} W_in[h][j] * coef(p,j) * W_out[o][h][p^j]
// one block per o; 256 threads stride over h; shuffle+LDS reduction
__global__ __launch_bounds__(256) void build_T_kernel(
    const float* __restrict__ W_in,   // [H][8]
    const float* __restrict__ W_out,  // [O][H][8]
    float* __restrict__ T,            // [O][8]
    int H)
{
    const int o = blockIdx.x;
    const int t = threadIdx.x;

    float acc[8];
#pragma unroll
    for (int p = 0; p < 8; ++p) acc[p] = 0.0f;

    for (int h = t; h < H; h += 256) {
        const float4* wi = reinterpret_cast<const float4*>(W_in + (size_t)h * 8);
        float4 a0 = wi[0], a1 = wi[1];
        const float4* wo = reinterpret_cast<const float4*>(W_out + ((size_t)o * H + h) * 8);
        float4 b0 = wo[0], b1 = wo[1];

        float win[8]  = {a0.x, a0.y, a0.z, a0.w, a1.x, a1.y, a1.z, a1.w};
        float wout[8] = {b0.x, b0.y, b0.z, b0.w, b1.x, b1.y, b1.z, b1.w};

#pragma unroll
        for (int p = 0; p < 8; ++p) {
            float s = 0.0f;
#pragma unroll
            for (int j = 0; j < 8; ++j) {
                s += coef_pj(p, j) * win[j] * wout[p ^ j];  // coef folds to +-1
            }
            acc[p] += s;
        }
    }

#pragma unroll
    for (int p = 0; p < 8; ++p) {
#pragma unroll
        for (int off = 32; off > 0; off >>= 1)
            acc[p] += __shfl_down(acc[p], off, 64);
    }

    __shared__ float lds[4][8];
    const int wave = t >> 6;
    const int lane = t & 63;
    if (lane == 0) {
#pragma unroll
        for (int p = 0; p < 8; ++p) lds[wave][p] = acc[p];
    }
    __syncthreads();
    if (t < 8) {
        float s = lds[0][t] + lds[1][t] + lds[2][t] + lds[3][t];
        T[o * 8 + t] = FREE_C * s;
    }
}

// out[b][o] = sum_p x[b][p] * T[o][p]
// One float4 of out per thread (4 consecutive o). T staged TRANSPOSED in LDS
// as Ts2[p][o] so each thread reads 8 x ds_read_b128; the 32 o-groups cover
// 512B contiguous per p-row, lanes 32..63 mirror lanes 0..31 (same-address
// broadcast = free). Stores are global_store_dwordx4, 16B/lane coalesced.
__global__ __launch_bounds__(256) void apply_T_kernel(
    const float* __restrict__ x,   // [B][8]
    const float* __restrict__ T,   // [O][8]
    float* __restrict__ out,       // [B][O]
    int B, int O)
{
    extern __shared__ float Ts2[];  // [8][O]
    const int tid = threadIdx.x;
    for (int idx = tid; idx < O * 8; idx += 256) {
        int oo = idx >> 3;
        int pp = idx & 7;
        Ts2[pp * O + oo] = T[idx];   // transpose-scatter (1024 elems, one-shot)
    }
    __syncthreads();

    const int OG = O >> 2;                  // o-groups of 4
    const int total4 = B * OG;              // float4 outputs
    const int stride = gridDim.x * 256;
    for (int i = blockIdx.x * 256 + tid; i < total4; i += stride) {
        const int b  = i / OG;
        const int og = i - b * OG;

        const float4* xp = reinterpret_cast<const float4*>(x + (size_t)b * 8);
        float4 x0 = xp[0], x1 = xp[1];
        float xs[8] = {x0.x, x0.y, x0.z, x0.w, x1.x, x1.y, x1.z, x1.w};

        float4 s = make_float4(0.f, 0.f, 0.f, 0.f);
#pragma unroll
        for (int p = 0; p < 8; ++p) {
            float4 tp = *reinterpret_cast<const float4*>(Ts2 + p * O + og * 4);
            s.x += xs[p] * tp.x;
            s.y += xs[p] * tp.y;
            s.z += xs[p] * tp.z;
            s.w += xs[p] * tp.w;
        }
        *reinterpret_cast<float4*>(out + (size_t)i * 4) = s;
    }
}

extern "C" void kernel_launch(void* const* d_in, const int* in_sizes, int n_in,
                              void* d_out, int out_size, void* d_ws, size_t ws_size,
                              hipStream_t stream) {
    const float* x_mv  = (const float*)d_in[0];  // [B,8]     f32
    const float* W_in  = (const float*)d_in[1];  // [H,1,8]   f32
    const float* W_out = (const float*)d_in[2];  // [O,H,8]   f32
    float* out = (float*)d_out;                  // [B,O]     f32

    const int B = in_sizes[0] / 8;
    const int H = in_sizes[1] / 8;
    const int O = in_sizes[2] / (8 * H);

    float* T = (float*)d_ws;  // O*8 floats (4 KB)

    build_T_kernel<<<O, 256, 0, stream>>>(W_in, W_out, T, H);

    const int total4 = B * (O >> 2);
    int grid = (total4 + 255) / 256;
    if (grid > 2048) grid = 2048;
    const size_t lds_bytes = (size_t)O * 8 * sizeof(float);
    apply_T_kernel<<<grid, 256, lds_bytes, stream>>>(x_mv, T, out, B, O);
}